// Round 2
// baseline (1006.494 us; speedup 1.0000x reference)
//
#include <hip/hip_runtime.h>
#include <hip/hip_bf16.h>
#include <stdint.h>

#define CLASSES 100000
#define CHANNEL 128
#define BATCH   4096
#define NPAD    100032   // 1563 * 64 (N padded to tile multiple)

typedef __bf16 bf16x8 __attribute__((ext_vector_type(8)));
typedef float  f32x4  __attribute__((ext_vector_type(4)));
typedef unsigned short u16x8 __attribute__((ext_vector_type(8)));

__device__ __forceinline__ unsigned short f32_to_bf16_rne(float f) {
    union { float f; uint32_t u; } v; v.f = f;
    uint32_t u = v.u;
    return (unsigned short)((u + 0x7fffu + ((u >> 16) & 1u)) >> 16);
}

// One wave per row: normalize x rows, write bf16.
__global__ void xnorm_kernel(const float* __restrict__ x, unsigned short* __restrict__ xn) {
    const int row  = blockIdx.x;
    const int lane = threadIdx.x;            // 0..63
    const float2 v = *reinterpret_cast<const float2*>(&x[(size_t)row * CHANNEL + lane * 2]);
    float s = v.x * v.x + v.y * v.y;
    #pragma unroll
    for (int off = 32; off >= 1; off >>= 1) s += __shfl_xor(s, off);
    const float inv = rsqrtf(fmaxf(s, 1e-12f));
    ushort2 o;
    o.x = f32_to_bf16_rne(v.x * inv);
    o.y = f32_to_bf16_rne(v.y * inv);
    *reinterpret_cast<ushort2*>(&xn[(size_t)row * CHANNEL + lane * 2]) = o;
}

// One thread per class-column: L2-normalize w column k, write transposed
// bf16 row wnt[k][0..127]. Two-pass read of w (second pass is L2/LLC-hot).
__global__ void wnorm_kernel(const float* __restrict__ w, unsigned short* __restrict__ wnt) {
    const int k = blockIdx.x * 256 + threadIdx.x;
    if (k >= NPAD) return;
    if (k >= CLASSES) {
        // zero-fill pad rows so MFMA on pad columns is harmless
        u16x8 z;
        #pragma unroll
        for (int i = 0; i < 8; ++i) z[i] = 0;
        #pragma unroll
        for (int c = 0; c < CHANNEL; c += 8)
            *reinterpret_cast<u16x8*>(&wnt[(size_t)k * CHANNEL + c]) = z;
        return;
    }
    float s = 0.f;
    #pragma unroll 8
    for (int c = 0; c < CHANNEL; ++c) {
        const float v = w[(size_t)c * CLASSES + k];
        s += v * v;
    }
    const float inv = rsqrtf(fmaxf(s, 1e-12f));
    #pragma unroll
    for (int c0 = 0; c0 < CHANNEL; c0 += 8) {
        u16x8 o;
        #pragma unroll
        for (int i = 0; i < 8; ++i) {
            const float v = w[(size_t)(c0 + i) * CLASSES + k];
            o[i] = f32_to_bf16_rne(v * inv);
        }
        *reinterpret_cast<u16x8*>(&wnt[(size_t)k * CHANNEL + c0]) = o;
    }
}

// 64 batch-rows x 64 classes per block; 4 waves, each: 16 batch-rows x 64 classes.
// OPERANDS SWAPPED vs R0: a = wnt (classes), b = xn (batch rows), so
// D.col(lane&15) = batch row, D.row((lane>>4)*4+reg) = class  ->
// each thread's acc[nf] holds 4 CONSECUTIVE classes of one output row
// -> one dwordx4 store per fragment, full-line coalescing through L2.
__global__ __launch_bounds__(256) void cos_gemm_kernel(const unsigned short* __restrict__ xn,
                                                       const unsigned short* __restrict__ wnt,
                                                       float* __restrict__ out) {
    const int bm   = blockIdx.x;     // 0..63   (M tiles; fastest -> consecutive blocks share wnt tile)
    const int bn   = blockIdx.y;     // 0..1562 (N tiles)
    const int tid  = threadIdx.x;
    const int wid  = tid >> 6;       // 0..3
    const int lane = tid & 63;
    const int l15  = lane & 15;
    const int lg   = lane >> 4;      // 0..3

    const int brow  = bm * 64 + wid * 16 + l15;   // batch row this lane's B-fragment carries
    const int ncol0 = bn * 64;
    const unsigned short* bp = &xn[(size_t)brow * CHANNEL + lg * 8];

    f32x4 acc[4] = {};
    #pragma unroll
    for (int ks = 0; ks < 4; ++ks) {
        const bf16x8 b = *reinterpret_cast<const bf16x8*>(bp + ks * 32);
        #pragma unroll
        for (int nf = 0; nf < 4; ++nf) {
            const unsigned short* ap =
                &wnt[(size_t)(ncol0 + nf * 16 + l15) * CHANNEL + ks * 32 + lg * 8];
            const bf16x8 a = *reinterpret_cast<const bf16x8*>(ap);
            acc[nf] = __builtin_amdgcn_mfma_f32_16x16x32_bf16(a, b, acc[nf], 0, 0, 0);
        }
    }

    // D layout: col = lane&15 (batch row), row = (lane>>4)*4 + reg (class)
    const int orow = bm * 64 + wid * 16 + l15;
    float* orp = &out[(size_t)orow * CLASSES];
    #pragma unroll
    for (int nf = 0; nf < 4; ++nf) {
        const int cbase = ncol0 + nf * 16 + lg * 4;
        if (cbase < CLASSES) {   // 100000 % 4 == 0 -> store is fully in or fully out
            *reinterpret_cast<f32x4*>(&orp[cbase]) = acc[nf];
        }
    }
}

extern "C" void kernel_launch(void* const* d_in, const int* in_sizes, int n_in,
                              void* d_out, int out_size, void* d_ws, size_t ws_size,
                              hipStream_t stream) {
    const float* x = (const float*)d_in[0];   // (4096, 128)
    const float* w = (const float*)d_in[1];   // (128, 100000)
    float* out = (float*)d_out;               // (4096, 100000)

    unsigned short* xn  = (unsigned short*)d_ws;                       // 4096*128 bf16 = 1 MiB
    unsigned short* wnt = xn + (size_t)BATCH * CHANNEL;                // 100032*128 bf16 = 25.6 MB
    const size_t need = ((size_t)BATCH * CHANNEL + (size_t)NPAD * CHANNEL) * sizeof(unsigned short);
    if (ws_size < need) return;  // insufficient scratch -> fail visibly rather than corrupt

    xnorm_kernel<<<dim3(BATCH), dim3(64), 0, stream>>>(x, xn);
    wnorm_kernel<<<dim3((NPAD + 255) / 256), dim3(256), 0, stream>>>(w, wnt);
    cos_gemm_kernel<<<dim3(64, 1563), dim3(256), 0, stream>>>(xn, wnt, out);
}

// Round 3
// 644.525 us; speedup vs baseline: 1.5616x; 1.5616x over previous
//
#include <hip/hip_runtime.h>
#include <hip/hip_bf16.h>
#include <stdint.h>

#define CLASSES 100000
#define CHANNEL 128
#define BATCH   4096
#define NPAD    100096   // 782 * 128 (class dim padded to 128-tile multiple)

typedef __bf16 bf16x8 __attribute__((ext_vector_type(8)));
typedef float  f32x4  __attribute__((ext_vector_type(4)));
typedef unsigned short u16x8 __attribute__((ext_vector_type(8)));

__device__ __forceinline__ unsigned short f32_to_bf16_rne(float f) {
    union { float f; uint32_t u; } v; v.f = f;
    uint32_t u = v.u;
    return (unsigned short)((u + 0x7fffu + ((u >> 16) & 1u)) >> 16);
}

// ---------------------------------------------------------------------------
// MFMA-fragment-tiled operand layout (both xn and wn):
//   element (frag16 f, k) stored at  [((f*4 + ks)*64 + lane)*8 + j]
//   where k = ks*32 + lg*8 + j, lane = lg*16 + l15, and l15 indexes the
//   16 rows/classes of the fragment. Every fragment load in the GEMM is then
//   one lane-contiguous 1 KB read (perfectly coalesced), instead of a
//   256 B-strided scatter (which was 64 L1 transactions per instruction and
//   made R0/R1 L1-request-rate-bound at ~1 ms).
// ---------------------------------------------------------------------------

// One wave per batch row: normalize, write bf16 into tiled layout.
__global__ void xnorm_kernel(const float* __restrict__ x, unsigned short* __restrict__ xnt) {
    const int row  = blockIdx.x * 4 + (threadIdx.x >> 6);
    const int lane = threadIdx.x & 63;
    const float2 v = *reinterpret_cast<const float2*>(&x[(size_t)row * CHANNEL + lane * 2]);
    float s = v.x * v.x + v.y * v.y;
    #pragma unroll
    for (int off = 32; off >= 1; off >>= 1) s += __shfl_xor(s, off);
    const float inv = rsqrtf(fmaxf(s, 1e-12f));
    const int rf  = row >> 4;
    const int l15 = row & 15;
    const int k0  = lane * 2;               // this lane holds k0, k0+1
    const int ks  = k0 >> 5;
    const int lg  = (k0 >> 3) & 3;
    const int j   = k0 & 7;
    ushort2 o;
    o.x = f32_to_bf16_rne(v.x * inv);
    o.y = f32_to_bf16_rne(v.y * inv);
    *reinterpret_cast<ushort2*>(
        &xnt[((size_t)(rf * 4 + ks) * 64 + lg * 16 + l15) * 8 + j]) = o;
}

// One thread per class: L2-normalize w column, write bf16 into tiled layout.
__global__ void wnorm_kernel(const float* __restrict__ w, unsigned short* __restrict__ wnt) {
    const int c = blockIdx.x * 256 + threadIdx.x;
    if (c >= NPAD) return;
    const int cf  = c >> 4;
    const int l15 = c & 15;
    if (c >= CLASSES) {
        u16x8 z;
        #pragma unroll
        for (int i = 0; i < 8; ++i) z[i] = 0;
        #pragma unroll
        for (int ks = 0; ks < 4; ++ks)
            #pragma unroll
            for (int lg = 0; lg < 4; ++lg)
                *reinterpret_cast<u16x8*>(
                    &wnt[((size_t)(cf * 4 + ks) * 64 + lg * 16 + l15) * 8]) = z;
        return;
    }
    float s = 0.f;
    #pragma unroll 8
    for (int ch = 0; ch < CHANNEL; ++ch) {
        const float v = w[(size_t)ch * CLASSES + c];
        s += v * v;
    }
    const float inv = rsqrtf(fmaxf(s, 1e-12f));
    #pragma unroll
    for (int ks = 0; ks < 4; ++ks) {
        #pragma unroll
        for (int lg = 0; lg < 4; ++lg) {
            u16x8 o;
            #pragma unroll
            for (int j = 0; j < 8; ++j) {
                const float v = w[(size_t)(ks * 32 + lg * 8 + j) * CLASSES + c];
                o[j] = f32_to_bf16_rne(v * inv);
            }
            *reinterpret_cast<u16x8*>(
                &wnt[((size_t)(cf * 4 + ks) * 64 + lg * 16 + l15) * 8]) = o;
        }
    }
}

// Block tile: 64 batch-rows x 128 classes. 4 waves in a 2x2 arrangement;
// each wave: 32 rows x 64 classes = 2 B-frags x 4 A-frags, 32 MFMAs.
// a = wn (classes), b = xn (rows)  =>  D: col(l15)=row, row(lg*4+j)=class
// so each thread's acc frag is 4 consecutive classes of one output row.
__global__ __launch_bounds__(256) void cos_gemm_kernel(const unsigned short* __restrict__ xnt,
                                                       const unsigned short* __restrict__ wnt,
                                                       float* __restrict__ out) {
    const int bm   = blockIdx.x;     // 0..63   (row tiles; fastest -> share wnt panel in L2)
    const int bn   = blockIdx.y;     // 0..781  (class tiles of 128)
    const int tid  = threadIdx.x;
    const int wv   = tid >> 6;
    const int wr   = wv >> 1;        // row half (0..1)
    const int wc   = wv & 1;         // class half (0..1)
    const int lane = tid & 63;
    const int l15  = lane & 15;
    const int lg   = lane >> 4;

    f32x4 acc[2][4] = {};
    #pragma unroll
    for (int ks = 0; ks < 4; ++ks) {
        bf16x8 b[2], a[4];
        #pragma unroll
        for (int bf = 0; bf < 2; ++bf) {
            const int rf = bm * 4 + wr * 2 + bf;
            b[bf] = *reinterpret_cast<const bf16x8*>(
                &xnt[((size_t)(rf * 4 + ks) * 64 + lane) * 8]);
        }
        #pragma unroll
        for (int af = 0; af < 4; ++af) {
            const int cf = bn * 8 + wc * 4 + af;
            a[af] = *reinterpret_cast<const bf16x8*>(
                &wnt[((size_t)(cf * 4 + ks) * 64 + lane) * 8]);
        }
        #pragma unroll
        for (int bf = 0; bf < 2; ++bf)
            #pragma unroll
            for (int af = 0; af < 4; ++af)
                acc[bf][af] = __builtin_amdgcn_mfma_f32_16x16x32_bf16(a[af], b[bf], acc[bf][af], 0, 0, 0);
    }

    #pragma unroll
    for (int bf = 0; bf < 2; ++bf) {
        const int row = bm * 64 + wr * 32 + bf * 16 + l15;
        float* orp = &out[(size_t)row * CLASSES];
        #pragma unroll
        for (int af = 0; af < 4; ++af) {
            const int cb = bn * 128 + wc * 64 + af * 16 + lg * 4;
            if (cb < CLASSES) {   // 100000 % 4 == 0: vector store fully in or out
                *reinterpret_cast<f32x4*>(&orp[cb]) = acc[bf][af];
            }
        }
    }
}

extern "C" void kernel_launch(void* const* d_in, const int* in_sizes, int n_in,
                              void* d_out, int out_size, void* d_ws, size_t ws_size,
                              hipStream_t stream) {
    const float* x = (const float*)d_in[0];   // (4096, 128)
    const float* w = (const float*)d_in[1];   // (128, 100000)
    float* out = (float*)d_out;               // (4096, 100000)

    unsigned short* xnt = (unsigned short*)d_ws;                  // 4096*128 bf16 = 1 MiB
    unsigned short* wnt = xnt + (size_t)BATCH * CHANNEL;          // 100096*128 bf16 = 25.6 MB
    const size_t need = ((size_t)BATCH * CHANNEL + (size_t)NPAD * CHANNEL) * sizeof(unsigned short);
    if (ws_size < need) return;  // insufficient scratch -> fail visibly rather than corrupt

    xnorm_kernel<<<dim3(BATCH / 4), dim3(256), 0, stream>>>(x, xnt);
    wnorm_kernel<<<dim3((NPAD + 255) / 256), dim3(256), 0, stream>>>(w, wnt);
    cos_gemm_kernel<<<dim3(64, 782), dim3(256), 0, stream>>>(xnt, wnt, out);
}

// Round 4
// 558.591 us; speedup vs baseline: 1.8018x; 1.1538x over previous
//
#include <hip/hip_runtime.h>
#include <hip/hip_bf16.h>
#include <stdint.h>

#define CLASSES 100000
#define CHANNEL 128
#define BATCH   4096
#define NPAD    100096   // 782 * 128 (class dim padded to 128-tile multiple)

typedef __bf16 bf16x8 __attribute__((ext_vector_type(8)));
typedef float  f32x4  __attribute__((ext_vector_type(4)));
typedef unsigned short u16x8 __attribute__((ext_vector_type(8)));

__device__ __forceinline__ unsigned short f32_to_bf16_rne(float f) {
    union { float f; uint32_t u; } v; v.f = f;
    uint32_t u = v.u;
    return (unsigned short)((u + 0x7fffu + ((u >> 16) & 1u)) >> 16);
}

// ---------------------------------------------------------------------------
// MFMA-fragment-tiled operand layout (both xn and wn):
//   element (frag16 f, k) stored at  [((f*4 + ks)*64 + lane)*8 + j]
//   so every GEMM fragment load is one lane-contiguous 1 KB read.
// ---------------------------------------------------------------------------

__global__ void xnorm_kernel(const float* __restrict__ x, unsigned short* __restrict__ xnt) {
    const int row  = blockIdx.x * 4 + (threadIdx.x >> 6);
    const int lane = threadIdx.x & 63;
    const float2 v = *reinterpret_cast<const float2*>(&x[(size_t)row * CHANNEL + lane * 2]);
    float s = v.x * v.x + v.y * v.y;
    #pragma unroll
    for (int off = 32; off >= 1; off >>= 1) s += __shfl_xor(s, off);
    const float inv = rsqrtf(fmaxf(s, 1e-12f));
    const int rf  = row >> 4;
    const int l15 = row & 15;
    const int k0  = lane * 2;
    const int ks  = k0 >> 5;
    const int lg  = (k0 >> 3) & 3;
    const int j   = k0 & 7;
    ushort2 o;
    o.x = f32_to_bf16_rne(v.x * inv);
    o.y = f32_to_bf16_rne(v.y * inv);
    *reinterpret_cast<ushort2*>(
        &xnt[((size_t)(rf * 4 + ks) * 64 + lg * 16 + l15) * 8 + j]) = o;
}

__global__ void wnorm_kernel(const float* __restrict__ w, unsigned short* __restrict__ wnt) {
    const int c = blockIdx.x * 256 + threadIdx.x;
    if (c >= NPAD) return;
    const int cf  = c >> 4;
    const int l15 = c & 15;
    if (c >= CLASSES) {
        u16x8 z;
        #pragma unroll
        for (int i = 0; i < 8; ++i) z[i] = 0;
        #pragma unroll
        for (int ks = 0; ks < 4; ++ks)
            #pragma unroll
            for (int lg = 0; lg < 4; ++lg)
                *reinterpret_cast<u16x8*>(
                    &wnt[((size_t)(cf * 4 + ks) * 64 + lg * 16 + l15) * 8]) = z;
        return;
    }
    float s = 0.f;
    #pragma unroll 8
    for (int ch = 0; ch < CHANNEL; ++ch) {
        const float v = w[(size_t)ch * CLASSES + c];
        s += v * v;
    }
    const float inv = rsqrtf(fmaxf(s, 1e-12f));
    #pragma unroll
    for (int ks = 0; ks < 4; ++ks) {
        #pragma unroll
        for (int lg = 0; lg < 4; ++lg) {
            u16x8 o;
            #pragma unroll
            for (int j = 0; j < 8; ++j) {
                const float v = w[(size_t)(ks * 32 + lg * 8 + j) * CLASSES + c];
                o[j] = f32_to_bf16_rne(v * inv);
            }
            *reinterpret_cast<u16x8*>(
                &wnt[((size_t)(cf * 4 + ks) * 64 + lg * 16 + l15) * 8]) = o;
        }
    }
}

// Block tile: 64 batch-rows x 128 classes; 4 waves (2x2), each 32 rows x 64 cols.
// NEW in R3: LDS-staged epilogue. Accs go to a padded 64x132 f32 LDS tile
// (both write and read patterns are exactly 8 dword-accesses per bank ->
// conflict-optimal), then each wave streams 16 rows with f32x4 stores where
// 32 consecutive lanes cover 512 B CONTIGUOUS per output row (full-line
// writes only; no dependence on L2 merging 64 B sectors across 16 rows).
#define LDSW 132
__global__ __launch_bounds__(256) void cos_gemm_kernel(const unsigned short* __restrict__ xnt,
                                                       const unsigned short* __restrict__ wnt,
                                                       float* __restrict__ out) {
    const int bm   = blockIdx.x;     // 0..63  (row tiles; fast dim -> wnt panel reuse in L2)
    const int bn   = blockIdx.y;     // 0..781 (class tiles of 128)
    const int tid  = threadIdx.x;
    const int wv   = tid >> 6;
    const int wr   = wv >> 1;        // row half (0..1)
    const int wc   = wv & 1;         // col half (0..1)
    const int lane = tid & 63;
    const int l15  = lane & 15;
    const int lg   = lane >> 4;

    __shared__ float lds[64 * LDSW];

    f32x4 acc[2][4] = {};
    #pragma unroll
    for (int ks = 0; ks < 4; ++ks) {
        bf16x8 b[2], a[4];
        #pragma unroll
        for (int bf = 0; bf < 2; ++bf) {
            const int rf = bm * 4 + wr * 2 + bf;
            b[bf] = *reinterpret_cast<const bf16x8*>(
                &xnt[((size_t)(rf * 4 + ks) * 64 + lane) * 8]);
        }
        #pragma unroll
        for (int af = 0; af < 4; ++af) {
            const int cf = bn * 8 + wc * 4 + af;
            a[af] = *reinterpret_cast<const bf16x8*>(
                &wnt[((size_t)(cf * 4 + ks) * 64 + lane) * 8]);
        }
        #pragma unroll
        for (int bf = 0; bf < 2; ++bf)
            #pragma unroll
            for (int af = 0; af < 4; ++af)
                acc[bf][af] = __builtin_amdgcn_mfma_f32_16x16x32_bf16(a[af], b[bf], acc[bf][af], 0, 0, 0);
    }

    // Stage accumulators to LDS. D layout: col(l15)=local row, row(lg*4+j)=local class.
    #pragma unroll
    for (int bf = 0; bf < 2; ++bf) {
        const int r = wr * 32 + bf * 16 + l15;
        #pragma unroll
        for (int af = 0; af < 4; ++af) {
            const int c = wc * 64 + af * 16 + lg * 4;
            *reinterpret_cast<f32x4*>(&lds[r * LDSW + c]) = acc[bf][af];
        }
    }
    __syncthreads();

    // Coalesced write-out: wave wv owns rows [wv*16, wv*16+16); per pass two
    // rows, 32 lanes x f32x4 = 512 B contiguous per row.
    const int half = lane >> 5;          // 0..1
    const int c4   = (lane & 31) * 4;    // 0..124
    #pragma unroll
    for (int p = 0; p < 8; ++p) {
        const int r   = wv * 16 + p * 2 + half;
        const int col = bn * 128 + c4;
        const f32x4 v = *reinterpret_cast<const f32x4*>(&lds[r * LDSW + c4]);
        if (col < CLASSES) {  // 100000 % 4 == 0: vector store fully in or out
            *reinterpret_cast<f32x4*>(&out[(size_t)(bm * 64 + r) * CLASSES + col]) = v;
        }
    }
}

extern "C" void kernel_launch(void* const* d_in, const int* in_sizes, int n_in,
                              void* d_out, int out_size, void* d_ws, size_t ws_size,
                              hipStream_t stream) {
    const float* x = (const float*)d_in[0];   // (4096, 128)
    const float* w = (const float*)d_in[1];   // (128, 100000)
    float* out = (float*)d_out;               // (4096, 100000)

    unsigned short* xnt = (unsigned short*)d_ws;                  // 4096*128 bf16 = 1 MiB
    unsigned short* wnt = xnt + (size_t)BATCH * CHANNEL;          // 100096*128 bf16 = 25.6 MB
    const size_t need = ((size_t)BATCH * CHANNEL + (size_t)NPAD * CHANNEL) * sizeof(unsigned short);
    if (ws_size < need) return;

    xnorm_kernel<<<dim3(BATCH / 4), dim3(256), 0, stream>>>(x, xnt);
    wnorm_kernel<<<dim3((NPAD + 255) / 256), dim3(256), 0, stream>>>(w, wnt);
    cos_gemm_kernel<<<dim3(64, 782), dim3(256), 0, stream>>>(xnt, wnt, out);
}

// Round 5
// 343.748 us; speedup vs baseline: 2.9280x; 1.6250x over previous
//
#include <hip/hip_runtime.h>
#include <hip/hip_bf16.h>
#include <stdint.h>

#define CLASSES 100000
#define CHANNEL 128
#define BATCH   4096
#define NPAD    100096   // 782 * 128 (class dim padded to 128-tile multiple)

typedef __bf16 bf16x8 __attribute__((ext_vector_type(8)));
typedef float  f32x4  __attribute__((ext_vector_type(4)));
typedef unsigned short u16x8 __attribute__((ext_vector_type(8)));

__device__ __forceinline__ unsigned short f32_to_bf16_rne(float f) {
    union { float f; uint32_t u; } v; v.f = f;
    uint32_t u = v.u;
    return (unsigned short)((u + 0x7fffu + ((u >> 16) & 1u)) >> 16);
}

// ---------------------------------------------------------------------------
// MFMA-fragment-tiled operand layout (both xn and wn):
//   element (frag16 f, k) stored at  [((f*4 + ks)*64 + lane)*8 + j]
//   so every GEMM fragment load is one lane-contiguous 1 KB read.
// ---------------------------------------------------------------------------

__global__ void xnorm_kernel(const float* __restrict__ x, unsigned short* __restrict__ xnt) {
    const int row  = blockIdx.x * 4 + (threadIdx.x >> 6);
    const int lane = threadIdx.x & 63;
    const float2 v = *reinterpret_cast<const float2*>(&x[(size_t)row * CHANNEL + lane * 2]);
    float s = v.x * v.x + v.y * v.y;
    #pragma unroll
    for (int off = 32; off >= 1; off >>= 1) s += __shfl_xor(s, off);
    const float inv = rsqrtf(fmaxf(s, 1e-12f));
    const int rf  = row >> 4;
    const int l15 = row & 15;
    const int k0  = lane * 2;
    const int ks  = k0 >> 5;
    const int lg  = (k0 >> 3) & 3;
    const int j   = k0 & 7;
    ushort2 o;
    o.x = f32_to_bf16_rne(v.x * inv);
    o.y = f32_to_bf16_rne(v.y * inv);
    *reinterpret_cast<ushort2*>(
        &xnt[((size_t)(rf * 4 + ks) * 64 + lg * 16 + l15) * 8 + j]) = o;
}

__global__ void wnorm_kernel(const float* __restrict__ w, unsigned short* __restrict__ wnt) {
    const int c = blockIdx.x * 256 + threadIdx.x;
    if (c >= NPAD) return;
    const int cf  = c >> 4;
    const int l15 = c & 15;
    if (c >= CLASSES) {
        u16x8 z;
        #pragma unroll
        for (int i = 0; i < 8; ++i) z[i] = 0;
        #pragma unroll
        for (int ks = 0; ks < 4; ++ks)
            #pragma unroll
            for (int lg = 0; lg < 4; ++lg)
                *reinterpret_cast<u16x8*>(
                    &wnt[((size_t)(cf * 4 + ks) * 64 + lg * 16 + l15) * 8]) = z;
        return;
    }
    float s = 0.f;
    #pragma unroll 8
    for (int ch = 0; ch < CHANNEL; ++ch) {
        const float v = w[(size_t)ch * CLASSES + c];
        s += v * v;
    }
    const float inv = rsqrtf(fmaxf(s, 1e-12f));
    #pragma unroll
    for (int ks = 0; ks < 4; ++ks) {
        #pragma unroll
        for (int lg = 0; lg < 4; ++lg) {
            u16x8 o;
            #pragma unroll
            for (int j = 0; j < 8; ++j) {
                const float v = w[(size_t)(ks * 32 + lg * 8 + j) * CLASSES + c];
                o[j] = f32_to_bf16_rne(v * inv);
            }
            *reinterpret_cast<u16x8*>(
                &wnt[((size_t)(cf * 4 + ks) * 64 + lg * 16 + l15) * 8]) = o;
        }
    }
}

// Block tile: 64 batch-rows x 128 classes; 4 waves (2x2), each 32 rows x 64 cols.
// R4: TWO-PHASE LDS epilogue (32 rows per phase, 16.9 KB LDS) -> 8 blocks/CU
// (was 4). More co-resident blocks overlap one block's load/MFMA phase with
// another's store burst, keeping the HBM write stream dense.
#define LDSW 132
__global__ __launch_bounds__(256) void cos_gemm_kernel(const unsigned short* __restrict__ xnt,
                                                       const unsigned short* __restrict__ wnt,
                                                       float* __restrict__ out) {
    const int bm   = blockIdx.x;     // 0..63  (row tiles; fast dim -> wnt panel reuse in L2)
    const int bn   = blockIdx.y;     // 0..781 (class tiles of 128)
    const int tid  = threadIdx.x;
    const int wv   = tid >> 6;
    const int wr   = wv >> 1;        // row half (0..1)
    const int wc   = wv & 1;         // col half (0..1)
    const int lane = tid & 63;
    const int l15  = lane & 15;
    const int lg   = lane >> 4;

    __shared__ float lds[32 * LDSW];

    f32x4 acc[2][4] = {};
    #pragma unroll
    for (int ks = 0; ks < 4; ++ks) {
        bf16x8 b[2], a[4];
        #pragma unroll
        for (int bf = 0; bf < 2; ++bf) {
            const int rf = bm * 4 + wr * 2 + bf;
            b[bf] = *reinterpret_cast<const bf16x8*>(
                &xnt[((size_t)(rf * 4 + ks) * 64 + lane) * 8]);
        }
        #pragma unroll
        for (int af = 0; af < 4; ++af) {
            const int cf = bn * 8 + wc * 4 + af;
            a[af] = *reinterpret_cast<const bf16x8*>(
                &wnt[((size_t)(cf * 4 + ks) * 64 + lane) * 8]);
        }
        #pragma unroll
        for (int bf = 0; bf < 2; ++bf)
            #pragma unroll
            for (int af = 0; af < 4; ++af)
                acc[bf][af] = __builtin_amdgcn_mfma_f32_16x16x32_bf16(a[af], b[bf], acc[bf][af], 0, 0, 0);
    }

    // Epilogue: phase ph stages rows [ph*32, ph*32+32) (held by waves wr==ph),
    // then all 4 waves stream them out, 2 rows x 512 B contiguous per store.
    const int  half = lane >> 5;          // 0..1
    const int  c4   = (lane & 31) * 4;    // 0..124
    const int  gcol = bn * 128 + c4;
    const bool colok = gcol < CLASSES;    // 100000 % 4 == 0: store fully in or out
    float* outbase = out + (size_t)(bm * 64) * CLASSES + gcol;

    #pragma unroll
    for (int ph = 0; ph < 2; ++ph) {
        if (ph) __syncthreads();          // drain phase-0 readers before overwrite
        if (wr == ph) {
            #pragma unroll
            for (int bf = 0; bf < 2; ++bf) {
                const int r = bf * 16 + l15;
                #pragma unroll
                for (int af = 0; af < 4; ++af)
                    *reinterpret_cast<f32x4*>(&lds[r * LDSW + wc * 64 + af * 16 + lg * 4]) = acc[bf][af];
            }
        }
        __syncthreads();
        #pragma unroll
        for (int p = 0; p < 4; ++p) {
            const int r = wv * 8 + p * 2 + half;   // 0..31
            const f32x4 v = *reinterpret_cast<const f32x4*>(&lds[r * LDSW + c4]);
            if (colok) {
                __builtin_nontemporal_store(
                    v, reinterpret_cast<f32x4*>(&outbase[(size_t)(ph * 32 + r) * CLASSES]));
            }
        }
    }
}

extern "C" void kernel_launch(void* const* d_in, const int* in_sizes, int n_in,
                              void* d_out, int out_size, void* d_ws, size_t ws_size,
                              hipStream_t stream) {
    const float* x = (const float*)d_in[0];   // (4096, 128)
    const float* w = (const float*)d_in[1];   // (128, 100000)
    float* out = (float*)d_out;               // (4096, 100000)

    unsigned short* xnt = (unsigned short*)d_ws;                  // 4096*128 bf16 = 1 MiB
    unsigned short* wnt = xnt + (size_t)BATCH * CHANNEL;          // 100096*128 bf16 = 25.6 MB
    const size_t need = ((size_t)BATCH * CHANNEL + (size_t)NPAD * CHANNEL) * sizeof(unsigned short);
    if (ws_size < need) return;

    xnorm_kernel<<<dim3(BATCH / 4), dim3(256), 0, stream>>>(x, xnt);
    wnorm_kernel<<<dim3((NPAD + 255) / 256), dim3(256), 0, stream>>>(w, wnt);
    cos_gemm_kernel<<<dim3(64, 782), dim3(256), 0, stream>>>(xnt, wnt, out);
}